// Round 1
// baseline (1831.056 us; speedup 1.0000x reference)
//
#include <hip/hip_runtime.h>
#include <stdint.h>

#define BATCH 64
#define TT    150
#define INSZ  120
#define HID   1024
#define OUTN  35
#define NBR   8
#define TPAD  160      // padded T (u64 masks), keeps chunk starts 64B-aligned
#define CH    8        // timesteps per chunk (19 chunks, last has 6 valid)
#define NCHUNK 19

// 8 x u64 in 16 consecutive SGPRs (one s_load_dwordx16)
typedef unsigned long long u64x8 __attribute__((ext_vector_type(8)));

// ---------------- workspace layout (bytes, all 64-aligned) ----------------
#define XT_OFF  0                  // xT  [150][120][64] f32 = 4,608,000
#define S1_OFF  4608000            // s1m [1024][160] u64    = 1,310,720
#define S2_OFF  5918720            // s2m
#define S3_OFF  7229440            // s3m
#define Y_OFF   8540160            // Y   [150][35][64] f32  = 1,344,000
#define ACC_OFF 9884160            // ACC [35][64] f32       = 8,960

// transpose x[b][0][t][i] -> xT[t][i][b], LDS-tiled (both sides coalesced)
__global__ __launch_bounds__(256) void k_tx(const float* __restrict__ x,
                                            float* __restrict__ xT) {
    const int t = blockIdx.x;
    __shared__ float tile[INSZ * 65];
    for (int e = threadIdx.x; e < INSZ * 64; e += 256) {
        const int b = e / INSZ, i = e - b * INSZ;
        tile[i * 65 + b] = x[((size_t)b * TT + t) * INSZ + i];
    }
    __syncthreads();
    for (int e = threadIdx.x; e < INSZ * 64; e += 256) {
        const int i = e >> 6, b = e & 63;
        xT[((size_t)t * INSZ + i) * 64 + b] = tile[i * 65 + b];
    }
}

// One recurrent layer, scans all T steps. grid = HID blocks x 512 threads.
// Block owns 1 neuron (8 branch rows); each wave (64 lanes = 64 batches)
// owns ONE row -> 8192 waves = 32 waves/CU (max occupancy).
// MODE 0: dense float input from xT. MODE 1: spike masks inm[i*TPAD + t].
// MODE 1 mask fetch: the row index ix is wave-uniform (readfirstlane), so the
// 64B of chunk masks are fetched with ONE s_load_dwordx16 straight into the
// SGPR tuple the v_cndmask "s" operands want — no VGPR round-trip, no
// v_readfirstlane marshalling (was ~21 wasted VALU ops per nonzero).
template <int DIN, int NNZ, int MODE>
__global__ __launch_bounds__(512, 8) void k_layer(
    const float* __restrict__ w,            // [HID*NBR, DIN]
    const void* __restrict__ maskp,         // [HID*NBR, DIN] bool (u8 or i32)
    const float* __restrict__ bias,         // [HID*NBR]
    const float* __restrict__ tau_m,        // [HID]
    const float* __restrict__ tau_n,        // [HID*NBR]
    const float* __restrict__ xin,          // MODE0: [T][DIN][64]
    const uint64_t* __restrict__ inm,       // MODE1: [DIN][TPAD]
    uint64_t* __restrict__ outm)            // [HID][TPAD]
{
    const int tid  = threadIdx.x;
    const int lane = tid & 63;
    const int wid  = tid >> 6;              // 0..7 (branch row)
    const int h    = blockIdx.x;
    const int r    = h * NBR + wid;         // this wave's row

    __shared__ uint2 ent[NBR * NNZ];        // (w bits, idx) per row
    __shared__ float red[2][NBR * CH * 64]; // double-buffered partial sums

    inm = (const uint64_t*)__builtin_assume_aligned(inm, 64);

    // ---- gather masked weights into LDS (ballot compaction) ----
    const unsigned char* m8  = (const unsigned char*)maskp;
    const int*           m32 = (const int*)maskp;
    {
        const int base = wid * NNZ;
        int cnt = 0;
        for (int c = 0; c * 64 < DIN; ++c) {
            const int i = c * 64 + lane;
            int   mv = 0;
            float wv = 0.f;
            if (i < DIN) {
                mv = m8[(size_t)r * DIN + i];
                wv = w[(size_t)r * DIN + i];
            }
            const unsigned long long bal = __ballot(mv != 0);
            const int pos = __popcll(bal & ((1ull << lane) - 1ull));
            if (mv && cnt + pos < NNZ)
                ent[base + cnt + pos] = make_uint2(__float_as_uint(wv), (unsigned)i);
            cnt += __popcll(bal);
        }
        if (cnt != NNZ) {   // masks are int32 after all
            cnt = 0;
            for (int c = 0; c * 64 < DIN; ++c) {
                const int i = c * 64 + lane;
                int   mv = 0;
                float wv = 0.f;
                if (i < DIN) {
                    mv = m32[(size_t)r * DIN + i];
                    wv = w[(size_t)r * DIN + i];
                }
                const unsigned long long bal = __ballot(mv != 0);
                const int pos = __popcll(bal & ((1ull << lane) - 1ull));
                if (mv) ent[base + cnt + pos] =
                            make_uint2(__float_as_uint(wv), (unsigned)i);
                cnt += __popcll(bal);
            }
        }
    }
    __syncthreads();

    const float be = 1.f / (1.f + expf(-tau_n[r]));
    const float om = 1.f - be;
    const float bb = bias[r];
    const float al  = 1.f / (1.f + expf(-tau_m[h]));
    const float oma = 1.f - al;

    float d = 0.f, mem = 0.f, spkprev = 0.f;
    const int base = wid * NNZ;

    for (int tc = 0; tc < NCHUNK; ++tc) {
        const int t0  = tc * CH;
        const int buf = tc & 1;
        float a[CH];
#pragma unroll
        for (int k = 0; k < CH; ++k) a[k] = 0.f;

        if constexpr (MODE == 1) {
#pragma unroll 4
            for (int j = 0; j < NNZ; ++j) {
                const uint2 e  = ent[base + j];
                const int   ix = __builtin_amdgcn_readfirstlane((int)e.y);
                const float wv = __uint_as_float(e.x);
                const uint64_t* p = inm + (size_t)ix * TPAD + t0;
                u64x8 mv;
                // scalar 64B fetch of 8 timestep masks; wait fused + tied to
                // the output so consumers can't be hoisted above it
                asm("s_load_dwordx16 %0, %1, 0x0\n\t"
                    "s_waitcnt lgkmcnt(0)"
                    : "=&s"(mv) : "s"(p));
#pragma unroll
                for (int k = 0; k < CH; ++k) {
                    float s;
                    asm("v_cndmask_b32 %0, 0, %1, %2"
                        : "=v"(s) : "v"(wv), "s"(mv[k]));
                    a[k] += s;
                }
            }
        } else {
            const float* xb = xin + (size_t)t0 * DIN * 64;
#pragma unroll 3
            for (int j = 0; j < NNZ; ++j) {
                const uint2 e  = ent[base + j];
                const int   ix = __builtin_amdgcn_readfirstlane((int)e.y);
                const float wv = __uint_as_float(e.x);
#pragma unroll
                for (int k = 0; k < CH; ++k)
                    a[k] += wv * xb[((size_t)k * DIN + ix) * 64 + lane];
            }
        }

        // branch decay (sequential within chunk), stash per-row d
#pragma unroll
        for (int k = 0; k < CH; ++k) {
            d = be * d + om * (a[k] + bb);
            red[buf][(wid * CH + k) * 64 + lane] = d;
        }
        // one barrier per chunk: waves 1..7 run chunk tc+1 into buf^1 while
        // wave 0 reduces buf; buf is rewritten only after the NEXT barrier.
        __syncthreads();

        if (wid == 0) {
#pragma unroll
            for (int k = 0; k < CH; ++k) {
                // EXACT old pair order: ((d0+d1)+(d2+d3))+(d4+d5))+(d6+d7)
                const float r0 = red[buf][(0 * CH + k) * 64 + lane];
                const float r1 = red[buf][(1 * CH + k) * 64 + lane];
                const float r2 = red[buf][(2 * CH + k) * 64 + lane];
                const float r3 = red[buf][(3 * CH + k) * 64 + lane];
                const float r4 = red[buf][(4 * CH + k) * 64 + lane];
                const float r5 = red[buf][(5 * CH + k) * 64 + lane];
                const float r6 = red[buf][(6 * CH + k) * 64 + lane];
                const float r7 = red[buf][(7 * CH + k) * 64 + lane];
                const float p01 = r0 + r1, p23 = r2 + r3;
                const float p45 = r4 + r5, p67 = r6 + r7;
                const float l = ((p01 + p23) + p45) + p67;
                if (t0 + k < TT) {
                    mem = al * mem + oma * l - spkprev;   // VTH = 1.0
                    spkprev = (mem > 1.0f) ? 1.f : 0.f;
                    const unsigned long long bal = __ballot(mem > 1.0f);
                    if (lane == 0) outm[(size_t)h * TPAD + (t0 + k)] = bal;
                }
            }
        }
    }
}

// Y[t][o][b] = wr[o] . s3(t,:,b); 4 waves split the i range (reorder safe:
// readout is linear, no thresholds downstream). wid goes through
// readfirstlane so LLVM knows the mask addresses are uniform; masks are
// fetched with scalar s_load_dwordx16 straight into SGPRs.
__global__ __launch_bounds__(256) void k_ry(const float* __restrict__ wr,
                                            const uint64_t* __restrict__ s3m,
                                            float* __restrict__ Y) {
    const int lane  = threadIdx.x & 63;
    const int wid   = __builtin_amdgcn_readfirstlane(threadIdx.x >> 6); // 0..3
    const int o  = blockIdx.x / NCHUNK;
    const int t0 = (blockIdx.x % NCHUNK) * CH;
    s3m = (const uint64_t*)__builtin_assume_aligned(s3m, 64);
    const float* wrow = wr + (size_t)o * HID;
    __shared__ float red[4 * CH * 64];
    float acc[CH];
#pragma unroll
    for (int k = 0; k < CH; ++k) acc[k] = 0.f;
#pragma unroll 4
    for (int ii = 0; ii < HID / 4; ++ii) {
        const int i = wid * (HID / 4) + ii;
        const float wv = wrow[i];
        const uint64_t* p = s3m + (size_t)i * TPAD + t0;
        u64x8 mv;
        asm("s_load_dwordx16 %0, %1, 0x0\n\t"
            "s_waitcnt lgkmcnt(0)"
            : "=&s"(mv) : "s"(p));
#pragma unroll
        for (int k = 0; k < CH; ++k) {
            float s;
            asm("v_cndmask_b32 %0, 0, %1, %2" : "=v"(s) : "v"(wv), "s"(mv[k]));
            acc[k] += s;
        }
    }
#pragma unroll
    for (int k = 0; k < CH; ++k)
        red[(wid * CH + k) * 64 + lane] = acc[k];
    __syncthreads();
    if (wid == 0) {
#pragma unroll
        for (int k = 0; k < CH; ++k) {
            if (t0 + k >= TT) break;
            const float v = ((red[(0 * CH + k) * 64 + lane]
                            + red[(1 * CH + k) * 64 + lane])
                            + red[(2 * CH + k) * 64 + lane])
                            + red[(3 * CH + k) * 64 + lane];
            Y[((size_t)(t0 + k) * OUTN + o) * 64 + lane] = v;
        }
    }
}

// acc[o][b] = sum_t (Y + br[o]) * (1 - ar^(150-t))   (closed-form mr scan)
__global__ void k_racc(const float* __restrict__ Y,
                       const float* __restrict__ br,
                       const float* __restrict__ tau_mr,
                       float* __restrict__ ACC) {
    const int o = blockIdx.x, lane = threadIdx.x;
    const float ar  = 1.f / (1.f + expf(-tau_mr[o]));
    const float bro = br[o];
    float acc = 0.f, q = ar;
    for (int t = TT - 1; t >= 0; --t) {
        const float y = Y[((size_t)t * OUTN + o) * 64 + lane] + bro;
        acc += y * (1.f - q);
        q *= ar;
    }
    ACC[o * 64 + lane] = acc;
}

__global__ void k_smax(const float* __restrict__ ACC, float* __restrict__ out) {
    const int b = threadIdx.x;   // 64 threads
    float v[OUTN];
    float mx = -3.4e38f;
    for (int o = 0; o < OUTN; ++o) {
        v[o] = ACC[o * 64 + b] / (float)TT;
        mx = fmaxf(mx, v[o]);
    }
    float sum = 0.f;
    for (int o = 0; o < OUTN; ++o) sum += expf(v[o] - mx);
    const float lse = mx + logf(sum);
    for (int o = 0; o < OUTN; ++o) out[b * OUTN + o] = v[o] - lse;
}

extern "C" void kernel_launch(void* const* d_in, const int* in_sizes, int n_in,
                              void* d_out, int out_size, void* d_ws,
                              size_t ws_size, hipStream_t stream) {
    (void)in_sizes; (void)n_in; (void)out_size; (void)ws_size;
    const float* x   = (const float*)d_in[0];
    const float* w1  = (const float*)d_in[1];
    const float* b1  = (const float*)d_in[2];
    const float* tm1 = (const float*)d_in[3];
    const float* tn1 = (const float*)d_in[4];
    const float* w2  = (const float*)d_in[5];
    const float* b2  = (const float*)d_in[6];
    const float* tm2 = (const float*)d_in[7];
    const float* tn2 = (const float*)d_in[8];
    const float* w3  = (const float*)d_in[9];
    const float* b3  = (const float*)d_in[10];
    const float* tm3 = (const float*)d_in[11];
    const float* tn3 = (const float*)d_in[12];
    const float* wr  = (const float*)d_in[13];
    const float* br  = (const float*)d_in[14];
    const float* tmr = (const float*)d_in[15];
    const void*  m1  = d_in[16];
    const void*  m2  = d_in[17];
    const void*  m3  = d_in[18];
    float* out = (float*)d_out;

    char* ws = (char*)d_ws;
    float*    xT  = (float*)(ws + XT_OFF);
    uint64_t* s1m = (uint64_t*)(ws + S1_OFF);
    uint64_t* s2m = (uint64_t*)(ws + S2_OFF);
    uint64_t* s3m = (uint64_t*)(ws + S3_OFF);
    float*    Y   = (float*)(ws + Y_OFF);
    float*    ACC = (float*)(ws + ACC_OFF);

    k_tx<<<TT, 256, 0, stream>>>(x, xT);
    k_layer<INSZ, 15, 0><<<HID, 512, 0, stream>>>(
        w1, m1, b1, tm1, tn1, xT, nullptr, s1m);
    k_layer<HID, 128, 1><<<HID, 512, 0, stream>>>(
        w2, m2, b2, tm2, tn2, nullptr, s1m, s2m);
    k_layer<HID, 128, 1><<<HID, 512, 0, stream>>>(
        w3, m3, b3, tm3, tn3, nullptr, s2m, s3m);
    k_ry<<<OUTN * NCHUNK, 256, 0, stream>>>(wr, s3m, Y);
    k_racc<<<OUTN, 64, 0, stream>>>(Y, br, tmr, ACC);
    k_smax<<<1, 64, 0, stream>>>(ACC, out);
}

// Round 2
// 1621.516 us; speedup vs baseline: 1.1292x; 1.1292x over previous
//
#include <hip/hip_runtime.h>
#include <stdint.h>

#define BATCH 64
#define TT    150
#define INSZ  120
#define HID   1024
#define OUTN  35
#define NBR   8
#define TPAD  160      // padded T (u64 masks), keeps chunk starts 64B-aligned
#define CH    8        // timesteps per chunk (19 chunks, last has 6 valid)
#define NCHUNK 19

// Constant-address-space alias: loads through this pointer are invariant and
// (with a uniform address) get scalarized to s_load_dwordx4/x8/x16 by LLVM,
// with compiler-managed lgkmcnt waits and cross-iteration pipelining.
typedef __attribute__((address_space(4))) const uint64_t cu64;

// ---------------- workspace layout (bytes, all 64-aligned) ----------------
#define XT_OFF  0                  // xT  [150][120][64] f32 = 4,608,000
#define S1_OFF  4608000            // s1m [1024][160] u64    = 1,310,720
#define S2_OFF  5918720            // s2m
#define S3_OFF  7229440            // s3m
#define Y_OFF   8540160            // Y   [150][35][64] f32  = 1,344,000
#define ACC_OFF 9884160            // ACC [35][64] f32       = 8,960

// transpose x[b][0][t][i] -> xT[t][i][b], LDS-tiled (both sides coalesced)
__global__ __launch_bounds__(256) void k_tx(const float* __restrict__ x,
                                            float* __restrict__ xT) {
    const int t = blockIdx.x;
    __shared__ float tile[INSZ * 65];
    for (int e = threadIdx.x; e < INSZ * 64; e += 256) {
        const int b = e / INSZ, i = e - b * INSZ;
        tile[i * 65 + b] = x[((size_t)b * TT + t) * INSZ + i];
    }
    __syncthreads();
    for (int e = threadIdx.x; e < INSZ * 64; e += 256) {
        const int i = e >> 6, b = e & 63;
        xT[((size_t)t * INSZ + i) * 64 + b] = tile[i * 65 + b];
    }
}

// One recurrent layer, scans all T steps. grid = HID blocks x 512 threads.
// Block owns 1 neuron (8 branch rows); each wave (64 lanes = 64 batches)
// owns ONE row -> 8192 waves = 32 waves/CU (max occupancy).
// MODE 0: dense float input from xT. MODE 1: spike masks inm[i*TPAD + t].
// MODE 1 mask fetch: ix is wave-uniform (readfirstlane); masks are read as
// plain loads through an AS(4) (constant) pointer so LLVM emits scalar
// s_load_dwordx16 straight into SGPRs — the v_cndmask "s" operands consume
// them with zero VGPR->SGPR marshalling and compiler-scheduled waits.
template <int DIN, int NNZ, int MODE>
__global__ __launch_bounds__(512, 8) void k_layer(
    const float* __restrict__ w,            // [HID*NBR, DIN]
    const void* __restrict__ maskp,         // [HID*NBR, DIN] bool (u8 or i32)
    const float* __restrict__ bias,         // [HID*NBR]
    const float* __restrict__ tau_m,        // [HID]
    const float* __restrict__ tau_n,        // [HID*NBR]
    const float* __restrict__ xin,          // MODE0: [T][DIN][64]
    const uint64_t* __restrict__ inm,       // MODE1: [DIN][TPAD]
    uint64_t* __restrict__ outm)            // [HID][TPAD]
{
    const int tid  = threadIdx.x;
    const int lane = tid & 63;
    const int wid  = tid >> 6;              // 0..7 (branch row)
    const int h    = blockIdx.x;
    const int r    = h * NBR + wid;         // this wave's row

    __shared__ uint2 ent[NBR * NNZ];        // (w bits, idx) per row
    __shared__ float red[2][NBR * CH * 64]; // double-buffered partial sums

    inm = (const uint64_t*)__builtin_assume_aligned(inm, 64);

    // ---- gather masked weights into LDS (ballot compaction) ----
    const unsigned char* m8  = (const unsigned char*)maskp;
    const int*           m32 = (const int*)maskp;
    {
        const int base = wid * NNZ;
        int cnt = 0;
        for (int c = 0; c * 64 < DIN; ++c) {
            const int i = c * 64 + lane;
            int   mv = 0;
            float wv = 0.f;
            if (i < DIN) {
                mv = m8[(size_t)r * DIN + i];
                wv = w[(size_t)r * DIN + i];
            }
            const unsigned long long bal = __ballot(mv != 0);
            const int pos = __popcll(bal & ((1ull << lane) - 1ull));
            if (mv && cnt + pos < NNZ)
                ent[base + cnt + pos] = make_uint2(__float_as_uint(wv), (unsigned)i);
            cnt += __popcll(bal);
        }
        if (cnt != NNZ) {   // masks are int32 after all
            cnt = 0;
            for (int c = 0; c * 64 < DIN; ++c) {
                const int i = c * 64 + lane;
                int   mv = 0;
                float wv = 0.f;
                if (i < DIN) {
                    mv = m32[(size_t)r * DIN + i];
                    wv = w[(size_t)r * DIN + i];
                }
                const unsigned long long bal = __ballot(mv != 0);
                const int pos = __popcll(bal & ((1ull << lane) - 1ull));
                if (mv) ent[base + cnt + pos] =
                            make_uint2(__float_as_uint(wv), (unsigned)i);
                cnt += __popcll(bal);
            }
        }
    }
    __syncthreads();

    const float be = 1.f / (1.f + expf(-tau_n[r]));
    const float om = 1.f - be;
    const float bb = bias[r];
    const float al  = 1.f / (1.f + expf(-tau_m[h]));
    const float oma = 1.f - al;

    float d = 0.f, mem = 0.f, spkprev = 0.f;
    const int base = wid * NNZ;

    for (int tc = 0; tc < NCHUNK; ++tc) {
        const int t0  = tc * CH;
        const int buf = tc & 1;
        float a[CH];
#pragma unroll
        for (int k = 0; k < CH; ++k) a[k] = 0.f;

        if constexpr (MODE == 1) {
#pragma unroll 4
            for (int j = 0; j < NNZ; ++j) {
                const uint2 e  = ent[base + j];
                const int   ix = __builtin_amdgcn_readfirstlane((int)e.y);
                const float wv = __uint_as_float(e.x);
                const cu64* p = (const cu64*)(inm + (size_t)ix * TPAD + t0);
                uint64_t m[CH];
#pragma unroll
                for (int k = 0; k < CH; ++k) m[k] = p[k];
#pragma unroll
                for (int k = 0; k < CH; ++k) {
                    float s;
                    asm("v_cndmask_b32 %0, 0, %1, %2"
                        : "=v"(s) : "v"(wv), "s"(m[k]));
                    a[k] += s;
                }
            }
        } else {
            const float* xb = xin + (size_t)t0 * DIN * 64;
#pragma unroll 3
            for (int j = 0; j < NNZ; ++j) {
                const uint2 e  = ent[base + j];
                const int   ix = __builtin_amdgcn_readfirstlane((int)e.y);
                const float wv = __uint_as_float(e.x);
#pragma unroll
                for (int k = 0; k < CH; ++k)
                    a[k] += wv * xb[((size_t)k * DIN + ix) * 64 + lane];
            }
        }

        // branch decay (sequential within chunk), stash per-row d
#pragma unroll
        for (int k = 0; k < CH; ++k) {
            d = be * d + om * (a[k] + bb);
            red[buf][(wid * CH + k) * 64 + lane] = d;
        }
        // one barrier per chunk: waves 1..7 run chunk tc+1 into buf^1 while
        // wave 0 reduces buf; buf is rewritten only after the NEXT barrier.
        __syncthreads();

        if (wid == 0) {
#pragma unroll
            for (int k = 0; k < CH; ++k) {
                // EXACT old pair order: ((d0+d1)+(d2+d3))+(d4+d5))+(d6+d7)
                const float r0 = red[buf][(0 * CH + k) * 64 + lane];
                const float r1 = red[buf][(1 * CH + k) * 64 + lane];
                const float r2 = red[buf][(2 * CH + k) * 64 + lane];
                const float r3 = red[buf][(3 * CH + k) * 64 + lane];
                const float r4 = red[buf][(4 * CH + k) * 64 + lane];
                const float r5 = red[buf][(5 * CH + k) * 64 + lane];
                const float r6 = red[buf][(6 * CH + k) * 64 + lane];
                const float r7 = red[buf][(7 * CH + k) * 64 + lane];
                const float p01 = r0 + r1, p23 = r2 + r3;
                const float p45 = r4 + r5, p67 = r6 + r7;
                const float l = ((p01 + p23) + p45) + p67;
                if (t0 + k < TT) {
                    mem = al * mem + oma * l - spkprev;   // VTH = 1.0
                    spkprev = (mem > 1.0f) ? 1.f : 0.f;
                    const unsigned long long bal = __ballot(mem > 1.0f);
                    if (lane == 0) outm[(size_t)h * TPAD + (t0 + k)] = bal;
                }
            }
        }
    }
}

// Y[t][o][b] = wr[o] . s3(t,:,b); 4 waves split the i range (reorder safe:
// readout is linear, no thresholds downstream). wid goes through
// readfirstlane so LLVM knows the mask addresses are uniform; masks are read
// through AS(4) pointers -> scalar s_load, no marshalling.
__global__ __launch_bounds__(256) void k_ry(const float* __restrict__ wr,
                                            const uint64_t* __restrict__ s3m,
                                            float* __restrict__ Y) {
    const int lane  = threadIdx.x & 63;
    const int wid   = __builtin_amdgcn_readfirstlane(threadIdx.x >> 6); // 0..3
    const int o  = blockIdx.x / NCHUNK;
    const int t0 = (blockIdx.x % NCHUNK) * CH;
    s3m = (const uint64_t*)__builtin_assume_aligned(s3m, 64);
    const float* wrow = wr + (size_t)o * HID;
    __shared__ float red[4 * CH * 64];
    float acc[CH];
#pragma unroll
    for (int k = 0; k < CH; ++k) acc[k] = 0.f;
#pragma unroll 4
    for (int ii = 0; ii < HID / 4; ++ii) {
        const int i = wid * (HID / 4) + ii;
        const float wv = wrow[i];
        const cu64* p = (const cu64*)(s3m + (size_t)i * TPAD + t0);
        uint64_t m[CH];
#pragma unroll
        for (int k = 0; k < CH; ++k) m[k] = p[k];
#pragma unroll
        for (int k = 0; k < CH; ++k) {
            float s;
            asm("v_cndmask_b32 %0, 0, %1, %2" : "=v"(s) : "v"(wv), "s"(m[k]));
            acc[k] += s;
        }
    }
#pragma unroll
    for (int k = 0; k < CH; ++k)
        red[(wid * CH + k) * 64 + lane] = acc[k];
    __syncthreads();
    if (wid == 0) {
#pragma unroll
        for (int k = 0; k < CH; ++k) {
            if (t0 + k >= TT) break;
            const float v = ((red[(0 * CH + k) * 64 + lane]
                            + red[(1 * CH + k) * 64 + lane])
                            + red[(2 * CH + k) * 64 + lane])
                            + red[(3 * CH + k) * 64 + lane];
            Y[((size_t)(t0 + k) * OUTN + o) * 64 + lane] = v;
        }
    }
}

// acc[o][b] = sum_t (Y + br[o]) * (1 - ar^(150-t))   (closed-form mr scan)
__global__ void k_racc(const float* __restrict__ Y,
                       const float* __restrict__ br,
                       const float* __restrict__ tau_mr,
                       float* __restrict__ ACC) {
    const int o = blockIdx.x, lane = threadIdx.x;
    const float ar  = 1.f / (1.f + expf(-tau_mr[o]));
    const float bro = br[o];
    float acc = 0.f, q = ar;
    for (int t = TT - 1; t >= 0; --t) {
        const float y = Y[((size_t)t * OUTN + o) * 64 + lane] + bro;
        acc += y * (1.f - q);
        q *= ar;
    }
    ACC[o * 64 + lane] = acc;
}

__global__ void k_smax(const float* __restrict__ ACC, float* __restrict__ out) {
    const int b = threadIdx.x;   // 64 threads
    float v[OUTN];
    float mx = -3.4e38f;
    for (int o = 0; o < OUTN; ++o) {
        v[o] = ACC[o * 64 + b] / (float)TT;
        mx = fmaxf(mx, v[o]);
    }
    float sum = 0.f;
    for (int o = 0; o < OUTN; ++o) sum += expf(v[o] - mx);
    const float lse = mx + logf(sum);
    for (int o = 0; o < OUTN; ++o) out[b * OUTN + o] = v[o] - lse;
}

extern "C" void kernel_launch(void* const* d_in, const int* in_sizes, int n_in,
                              void* d_out, int out_size, void* d_ws,
                              size_t ws_size, hipStream_t stream) {
    (void)in_sizes; (void)n_in; (void)out_size; (void)ws_size;
    const float* x   = (const float*)d_in[0];
    const float* w1  = (const float*)d_in[1];
    const float* b1  = (const float*)d_in[2];
    const float* tm1 = (const float*)d_in[3];
    const float* tn1 = (const float*)d_in[4];
    const float* w2  = (const float*)d_in[5];
    const float* b2  = (const float*)d_in[6];
    const float* tm2 = (const float*)d_in[7];
    const float* tn2 = (const float*)d_in[8];
    const float* w3  = (const float*)d_in[9];
    const float* b3  = (const float*)d_in[10];
    const float* tm3 = (const float*)d_in[11];
    const float* tn3 = (const float*)d_in[12];
    const float* wr  = (const float*)d_in[13];
    const float* br  = (const float*)d_in[14];
    const float* tmr = (const float*)d_in[15];
    const void*  m1  = d_in[16];
    const void*  m2  = d_in[17];
    const void*  m3  = d_in[18];
    float* out = (float*)d_out;

    char* ws = (char*)d_ws;
    float*    xT  = (float*)(ws + XT_OFF);
    uint64_t* s1m = (uint64_t*)(ws + S1_OFF);
    uint64_t* s2m = (uint64_t*)(ws + S2_OFF);
    uint64_t* s3m = (uint64_t*)(ws + S3_OFF);
    float*    Y   = (float*)(ws + Y_OFF);
    float*    ACC = (float*)(ws + ACC_OFF);

    k_tx<<<TT, 256, 0, stream>>>(x, xT);
    k_layer<INSZ, 15, 0><<<HID, 512, 0, stream>>>(
        w1, m1, b1, tm1, tn1, xT, nullptr, s1m);
    k_layer<HID, 128, 1><<<HID, 512, 0, stream>>>(
        w2, m2, b2, tm2, tn2, nullptr, s1m, s2m);
    k_layer<HID, 128, 1><<<HID, 512, 0, stream>>>(
        w3, m3, b3, tm3, tn3, nullptr, s2m, s3m);
    k_ry<<<OUTN * NCHUNK, 256, 0, stream>>>(wr, s3m, Y);
    k_racc<<<OUTN, 64, 0, stream>>>(Y, br, tmr, ACC);
    k_smax<<<1, 64, 0, stream>>>(ACC, out);
}